// Round 22
// baseline (856.962 us; speedup 1.0000x reference)
//
#include <hip/hip_runtime.h>
#include <hip/hip_bf16.h>

typedef __bf16 bf16x8 __attribute__((ext_vector_type(8)));
typedef float  f32x4  __attribute__((ext_vector_type(4)));
typedef float  f32x2  __attribute__((ext_vector_type(2)));
typedef float  f32x16 __attribute__((ext_vector_type(16)));
typedef int    i32x4  __attribute__((ext_vector_type(4)));

// paired gelu: per-component op sequence identical to the R2/R5-proven scalar path
__device__ __forceinline__ f32x2 gelu2(f32x2 x) {
    f32x2 x2 = x * x;                               // v_pk_mul_f32
    f32x2 t  = x2 * 0.044715f + 1.0f;               // v_pk_fma_f32
    f32x2 a  = (x * -1.5957691216057308f) * t;      // same assoc as scalar path
    f32x2 e  = { __expf(a.x), __expf(a.y) };
    f32x2 d  = e + 1.0f;                            // v_pk_add_f32
    f32x2 r  = { __builtin_amdgcn_rcpf(d.x), __builtin_amdgcn_rcpf(d.y) };
    return x * r;                                   // v_pk_mul_f32
}

// two scalar RNE casts + bit assembly (value-identical to scalar stores)
__device__ __forceinline__ unsigned int pack2bf(float a, float b) {
    unsigned short ua = __builtin_bit_cast(unsigned short, (__bf16)a);
    unsigned short ub = __builtin_bit_cast(unsigned short, (__bf16)b);
    return (unsigned int)ua | ((unsigned int)ub << 16);
}

// C-fragment (32x32, rows u) -> B-fragment (k=u) conversion, verified R7-R21
__device__ __forceinline__ bf16x8 frag_from_pk(unsigned int q0, unsigned int q1,
                                               unsigned int q2, unsigned int q3) {
    auto p02 = __builtin_amdgcn_permlane32_swap((int)q0, (int)q2, false, false);
    auto p13 = __builtin_amdgcn_permlane32_swap((int)q1, (int)q3, false, false);
    i32x4 fri = { static_cast<int>(p02[0]), static_cast<int>(p13[0]),
                  static_cast<int>(p02[1]), static_cast<int>(p13[1]) };
    return __builtin_bit_cast(bf16x8, fri);
}

// w2t[u][k] = W2[k][u]  bf16, 32768 elems
// w3t[d][u] = W3[u][d] (d<3 else 0) bf16 padded to 32 rows, 8192 elems
// w1tp[u][k] = W1[k][u] (k<3), b1[u] at k=3, else 0 (bf16, K=16), 2048 elems
__global__ void prep_weights(const float* __restrict__ W2, const float* __restrict__ W3,
                             const float* __restrict__ W1, const float* __restrict__ b1,
                             __bf16* __restrict__ w2t, __bf16* __restrict__ w3t,
                             __bf16* __restrict__ w1tp) {
    int idx = blockIdx.x * 256 + threadIdx.x;
    if (idx < 32768) {
        int k = idx >> 8;
        int u = idx & 255;
        w2t[u * 128 + k] = (__bf16)W2[idx];
    } else if (idx < 32768 + 8192) {
        int t = idx - 32768;
        int d = t >> 8;
        int u = t & 255;
        w3t[t] = (__bf16)(d < 3 ? W3[u * 3 + d] : 0.0f);
    } else if (idx < 32768 + 8192 + 2048) {
        int t = idx - 40960;
        int u = t >> 4;
        int k = t & 15;
        float v = (k < 3) ? W1[k * 128 + u] : (k == 3 ? b1[u] : 0.0f);
        w1tp[t] = (__bf16)v;
    }
}

__launch_bounds__(512, 4)
__global__ void edge_mlp(const float* __restrict__ y, const float* __restrict__ x,
                         const float* __restrict__ fy,
                         const int* __restrict__ nbr, const int* __restrict__ xidx,
                         const __bf16* __restrict__ w1tp,
                         const __bf16* __restrict__ w2t, const float* __restrict__ b2,
                         const __bf16* __restrict__ w3t, const float* __restrict__ b3,
                         float* __restrict__ out, int E) {
    __shared__ __attribute__((aligned(16))) __bf16 w2l[256 * 128];   // 64 KB, XOR-swizzled
    __shared__ __attribute__((aligned(16))) float b2s[256];

    const int tid  = threadIdx.x;
    const int wid  = tid >> 6;
    const int lane = tid & 63;
    const int l31  = lane & 31;
    const int b    = lane >> 5;

    // ---- stage W2 -> LDS ONCE (swizzled) + b2; amortized over 2 edge tiles ----
    {
        int u = tid >> 1, half = tid & 1;
        const __bf16* src = w2t + u * 128 + half * 64;
        char* rowbase = (char*)w2l + u * 256;
        int sw = (u & 15) << 4;
        #pragma unroll
        for (int j = 0; j < 8; ++j) {
            bf16x8 v = *(const bf16x8*)(src + j * 8);
            *(bf16x8*)(rowbase + ((half * 128 + j * 16) ^ sw)) = v;
        }
    }
    if (tid < 256) b2s[tid] = b2[tid];
    __syncthreads();   // w2l + b2s visible; read-only afterwards

    // ---- exactly two edge tiles per block; all per-tile state scoped inside ----
    #pragma unroll 1
    for (int t = 0; t < 2; ++t) {
        const int g = (2 * blockIdx.x + t) * 256 + wid * 32 + l31;

        // gather this wave's 32 edges (b==0 lanes own them); rel stays in regs
        int   iidx = -1;
        float fy0 = 0.0f, fy1 = 0.0f, fy2 = 0.0f;
        bf16x8 rv = { (__bf16)0.0f, (__bf16)0.0f, (__bf16)0.0f, (__bf16)0.0f,
                      (__bf16)0.0f, (__bf16)0.0f, (__bf16)0.0f, (__bf16)0.0f };
        if (b == 0) {
            if (g < E) {
                int j = nbr[g];
                iidx  = xidx[g];
                rv[0] = (__bf16)(y[j*3+0] - x[iidx*3+0]);
                rv[1] = (__bf16)(y[j*3+1] - x[iidx*3+1]);
                rv[2] = (__bf16)(y[j*3+2] - x[iidx*3+2]);
                fy0 = fy[j*3+0];
                fy1 = fy[j*3+1];
                fy2 = fy[j*3+2];
            }
            rv[3] = (__bf16)1.0f;   // bias column: h1 = rel@W1 + 1*b1 inside the MFMA
        }
        const bf16x8 relB = rv;     // lane-local layer-1 B-frag (R14/R15-proven)

        // ---- layer 1 via MFMA (32x32x16, K=4 used): C = h1^T[u][e], bias via k=3 ----
        bf16x8 B2[8];   // layer-2 B-fragments, in-register
        #pragma unroll
        for (int ut1 = 0; ut1 < 4; ++ut1) {
            f32x16 c;
            #pragma unroll
            for (int q = 0; q < 16; ++q) c[q] = 0.0f;
            bf16x8 a1 = *(const bf16x8*)&w1tp[(ut1 * 32 + l31) * 16 + b * 8];
            c = __builtin_amdgcn_mfma_f32_32x32x16_bf16(a1, relB, c, 0, 0, 0);

            unsigned int pw[8];
            #pragma unroll
            for (int gq = 0; gq < 4; ++gq) {
                f32x2 g01 = gelu2((f32x2){ c[4*gq+0], c[4*gq+1] });
                f32x2 g23 = gelu2((f32x2){ c[4*gq+2], c[4*gq+3] });
                pw[2*gq+0] = pack2bf(g01.x, g01.y);
                pw[2*gq+1] = pack2bf(g23.x, g23.y);
            }
            B2[2*ut1+0] = frag_from_pk(pw[0], pw[1], pw[2], pw[3]);
            B2[2*ut1+1] = frag_from_pk(pw[4], pw[5], pw[6], pw[7]);
        }

        // ---- layers 2+3 fused per 32-u slice; A2 from swizzled LDS; b2 in C-init ----
        f32x16 acc3;
        #pragma unroll
        for (int q = 0; q < 16; ++q) acc3[q] = 0.0f;

        #pragma unroll
        for (int ut = 0; ut < 8; ++ut) {
            int u0 = ut * 32 + 4 * b;
            f32x16 c;
            #pragma unroll
            for (int gq = 0; gq < 4; ++gq) {
                f32x4 bq = *(const f32x4*)&b2s[u0 + 8 * gq];   // LDS broadcast
                c[4*gq+0] = bq[0]; c[4*gq+1] = bq[1]; c[4*gq+2] = bq[2]; c[4*gq+3] = bq[3];
            }
            {
                const int u = ut * 32 + l31;
                const char* rowbase = (const char*)w2l + u * 256;
                const int sw = (u & 15) << 4;
                #pragma unroll
                for (int kt = 0; kt < 8; ++kt) {
                    bf16x8 a2 = *(const bf16x8*)(rowbase + ((kt * 32 + b * 16) ^ sw));
                    c = __builtin_amdgcn_mfma_f32_32x32x16_bf16(a2, B2[kt], c, 0, 0, 0);
                }
            }

            unsigned int pw[8];
            #pragma unroll
            for (int gq = 0; gq < 4; ++gq) {
                f32x2 g01 = gelu2((f32x2){ c[4*gq+0], c[4*gq+1] });
                f32x2 g23 = gelu2((f32x2){ c[4*gq+2], c[4*gq+3] });
                pw[2*gq+0] = pack2bf(g01.x, g01.y);
                pw[2*gq+1] = pack2bf(g23.x, g23.y);
            }

            #pragma unroll
            for (int ki = 0; ki < 2; ++ki) {
                bf16x8 bfr = frag_from_pk(pw[4*ki+0], pw[4*ki+1], pw[4*ki+2], pw[4*ki+3]);
                bf16x8 a3  = *(const bf16x8*)&w3t[l31 * 256 + ut * 32 + ki * 16 + b * 8];
                acc3 = __builtin_amdgcn_mfma_f32_32x32x16_bf16(a3, bfr, acc3, 0, 0, 0);
            }
        }

        // ---- output: b==0 lane l31 owns edge g; shfl segmented scan, tail atomics ----
        if (b == 0) {
            float m0 = 0.0f, m1 = 0.0f, m2 = 0.0f;
            if (iidx >= 0) {
                m0 = (acc3[0] + b3[0]) * fy0;
                m1 = (acc3[1] + b3[1]) * fy1;
                m2 = (acc3[2] + b3[2]) * fy2;
            }
            // inclusive segmented scan over lanes 0..31 (x_index sorted)
            #pragma unroll
            for (int d = 1; d < 32; d <<= 1) {
                int   oi = __shfl(iidx, l31 - d, 64);
                float o0 = __shfl(m0,   l31 - d, 64);
                float o1 = __shfl(m1,   l31 - d, 64);
                float o2 = __shfl(m2,   l31 - d, 64);
                if (l31 >= d && oi == iidx) { m0 += o0; m1 += o1; m2 += o2; }
            }
            int ni = __shfl(iidx, l31 + 1, 64);   // lane 31 reads lane 32 (b=1, iidx=-1)
            bool tail = (iidx >= 0) && (l31 == 31 || ni != iidx);
            if (tail) {
                unsafeAtomicAdd(&out[iidx*3+0], m0);
                unsafeAtomicAdd(&out[iidx*3+1], m1);
                unsafeAtomicAdd(&out[iidx*3+2], m2);
            }
        }
    }
}

// out[i] /= max(cnt_i, 1); cnt via binary search on sorted x_index
__global__ void finalize_div(float* __restrict__ out, const int* __restrict__ xidx,
                             int E, int nx) {
    int i = blockIdx.x * blockDim.x + threadIdx.x;
    if (i >= nx) return;
    int lo = 0, hi = E;
    while (lo < hi) { int mid = (lo + hi) >> 1; if (xidx[mid] < i) lo = mid + 1; else hi = mid; }
    int start = lo;
    hi = E;
    while (lo < hi) { int mid = (lo + hi) >> 1; if (xidx[mid] < i + 1) lo = mid + 1; else hi = mid; }
    int cnt = lo - start;
    float inv = 1.0f / (float)(cnt > 1 ? cnt : 1);
    out[i*3+0] *= inv;
    out[i*3+1] *= inv;
    out[i*3+2] *= inv;
}

extern "C" void kernel_launch(void* const* d_in, const int* in_sizes, int n_in,
                              void* d_out, int out_size, void* d_ws, size_t ws_size,
                              hipStream_t stream) {
    const float* y   = (const float*)d_in[0];
    const float* x   = (const float*)d_in[1];
    const float* fyp = (const float*)d_in[2];
    const int*   nbr = (const int*)d_in[3];
    const int*   xix = (const int*)d_in[4];
    const float* W1  = (const float*)d_in[5];
    const float* b1  = (const float*)d_in[6];
    const float* W2  = (const float*)d_in[7];
    const float* b2  = (const float*)d_in[8];
    const float* W3  = (const float*)d_in[9];
    const float* b3  = (const float*)d_in[10];
    float* out = (float*)d_out;

    int E  = in_sizes[3];
    int nx = in_sizes[1] / 3;
    __bf16* w2t  = (__bf16*)d_ws;                        // 32768 bf16 = 64 KB
    __bf16* w3t  = (__bf16*)((char*)d_ws + 65536);       // 8192 bf16 = 16 KB
    __bf16* w1tp = (__bf16*)((char*)d_ws + 81920);       // 2048 bf16 = 4 KB

    hipMemsetAsync(d_out, 0, (size_t)out_size * sizeof(float), stream);
    prep_weights<<<168, 256, 0, stream>>>(W2, W3, W1, b1, w2t, w3t, w1tp);

    int nblocks = (E + 511) / 512;    // 2 edge tiles (512 edges) per block
    edge_mlp<<<nblocks, 512, 0, stream>>>(y, x, fyp, nbr, xix, w1tp, w2t, b2, w3t, b3, out, E);

    finalize_div<<<(nx + 255) / 256, 256, 0, stream>>>(out, xix, E, nx);
}

// Round 23
// 136.666 us; speedup vs baseline: 6.2705x; 6.2705x over previous
//
#include <hip/hip_runtime.h>
#include <hip/hip_bf16.h>

typedef __bf16 bf16x8 __attribute__((ext_vector_type(8)));
typedef float  f32x4  __attribute__((ext_vector_type(4)));
typedef float  f32x2  __attribute__((ext_vector_type(2)));
typedef float  f32x16 __attribute__((ext_vector_type(16)));
typedef int    i32x4  __attribute__((ext_vector_type(4)));

// paired gelu: per-component op sequence identical to the R2/R5-proven scalar path
__device__ __forceinline__ f32x2 gelu2(f32x2 x) {
    f32x2 x2 = x * x;                               // v_pk_mul_f32
    f32x2 t  = x2 * 0.044715f + 1.0f;               // v_pk_fma_f32
    f32x2 a  = (x * -1.5957691216057308f) * t;      // same assoc as scalar path
    f32x2 e  = { __expf(a.x), __expf(a.y) };
    f32x2 d  = e + 1.0f;                            // v_pk_add_f32
    f32x2 r  = { __builtin_amdgcn_rcpf(d.x), __builtin_amdgcn_rcpf(d.y) };
    return x * r;                                   // v_pk_mul_f32
}

// two scalar RNE casts + bit assembly (value-identical to scalar stores)
__device__ __forceinline__ unsigned int pack2bf(float a, float b) {
    unsigned short ua = __builtin_bit_cast(unsigned short, (__bf16)a);
    unsigned short ub = __builtin_bit_cast(unsigned short, (__bf16)b);
    return (unsigned int)ua | ((unsigned int)ub << 16);
}

// C-fragment (32x32, rows u) -> B-fragment (k=u) conversion, verified R7-R21
__device__ __forceinline__ bf16x8 frag_from_pk(unsigned int q0, unsigned int q1,
                                               unsigned int q2, unsigned int q3) {
    auto p02 = __builtin_amdgcn_permlane32_swap((int)q0, (int)q2, false, false);
    auto p13 = __builtin_amdgcn_permlane32_swap((int)q1, (int)q3, false, false);
    i32x4 fri = { static_cast<int>(p02[0]), static_cast<int>(p13[0]),
                  static_cast<int>(p02[1]), static_cast<int>(p13[1]) };
    return __builtin_bit_cast(bf16x8, fri);
}

// w2t[u][k] = W2[k][u]  bf16, 32768 elems
// w3t[d][u] = W3[u][d] (d<3 else 0) bf16 padded to 32 rows, 8192 elems
// w1tp[u][k] = W1[k][u] (k<3), b1[u] at k=3, else 0 (bf16, K=16), 2048 elems
__global__ void prep_weights(const float* __restrict__ W2, const float* __restrict__ W3,
                             const float* __restrict__ W1, const float* __restrict__ b1,
                             __bf16* __restrict__ w2t, __bf16* __restrict__ w3t,
                             __bf16* __restrict__ w1tp) {
    int idx = blockIdx.x * 256 + threadIdx.x;
    if (idx < 32768) {
        int k = idx >> 8;
        int u = idx & 255;
        w2t[u * 128 + k] = (__bf16)W2[idx];
    } else if (idx < 32768 + 8192) {
        int t = idx - 32768;
        int d = t >> 8;
        int u = t & 255;
        w3t[t] = (__bf16)(d < 3 ? W3[u * 3 + d] : 0.0f);
    } else if (idx < 32768 + 8192 + 2048) {
        int t = idx - 40960;
        int u = t >> 4;
        int k = t & 15;
        float v = (k < 3) ? W1[k * 128 + u] : (k == 3 ? b1[u] : 0.0f);
        w1tp[t] = (__bf16)v;
    }
}

__launch_bounds__(512, 4)
__global__ void edge_mlp(const float* __restrict__ y, const float* __restrict__ x,
                         const float* __restrict__ fy,
                         const int* __restrict__ nbr, const int* __restrict__ xidx,
                         const __bf16* __restrict__ w1tp,
                         const __bf16* __restrict__ w2t, const float* __restrict__ b2,
                         const __bf16* __restrict__ w3t, const float* __restrict__ b3,
                         float* __restrict__ out, int E) {
    __shared__ __attribute__((aligned(16))) __bf16 w2l[256 * 128];   // 64 KB, XOR-swizzled
    __shared__ __attribute__((aligned(16))) float b2s[256];

    const int tid  = threadIdx.x;
    const int wid  = tid >> 6;
    const int lane = tid & 63;
    const int l31  = lane & 31;
    const int b    = lane >> 5;

    // ---- stage W2 -> LDS (swizzled) + b2 ----
    {
        int u = tid >> 1, half = tid & 1;
        const __bf16* src = w2t + u * 128 + half * 64;
        char* rowbase = (char*)w2l + u * 256;
        int sw = (u & 15) << 4;
        #pragma unroll
        for (int j = 0; j < 8; ++j) {
            bf16x8 v = *(const bf16x8*)(src + j * 8);
            *(bf16x8*)(rowbase + ((half * 128 + j * 16) ^ sw)) = v;
        }
    }
    if (tid < 256) b2s[tid] = b2[tid];

    // ---- gather this wave's 32 edges (b==0 lanes own them); rel stays in regs ----
    const int g = blockIdx.x * 256 + wid * 32 + l31;
    int   iidx = -1;
    float fy0 = 0.0f, fy1 = 0.0f, fy2 = 0.0f;
    bf16x8 rv = { (__bf16)0.0f, (__bf16)0.0f, (__bf16)0.0f, (__bf16)0.0f,
                  (__bf16)0.0f, (__bf16)0.0f, (__bf16)0.0f, (__bf16)0.0f };
    if (b == 0) {
        if (g < E) {
            int j = nbr[g];
            iidx  = xidx[g];
            rv[0] = (__bf16)(y[j*3+0] - x[iidx*3+0]);
            rv[1] = (__bf16)(y[j*3+1] - x[iidx*3+1]);
            rv[2] = (__bf16)(y[j*3+2] - x[iidx*3+2]);
            fy0 = fy[j*3+0];
            fy1 = fy[j*3+1];
            fy2 = fy[j*3+2];
        }
        rv[3] = (__bf16)1.0f;   // bias column: h1 = rel@W1 + 1*b1 inside the MFMA
    }
    // layer-1 B-frag IS rv (lane-local; R14/R15-proven); k=3 carries the bias input
    const bf16x8 relB = rv;
    __syncthreads();   // w2l + b2s visible

    // ---- layer 1 via MFMA (32x32x16, K=4 used): C = h1^T[u][e], bias via k=3 ----
    bf16x8 B2[8];   // layer-2 B-fragments, in-register
    #pragma unroll
    for (int ut1 = 0; ut1 < 4; ++ut1) {
        f32x16 c;
        #pragma unroll
        for (int q = 0; q < 16; ++q) c[q] = 0.0f;
        bf16x8 a1 = *(const bf16x8*)&w1tp[(ut1 * 32 + l31) * 16 + b * 8];
        c = __builtin_amdgcn_mfma_f32_32x32x16_bf16(a1, relB, c, 0, 0, 0);

        unsigned int pw[8];
        #pragma unroll
        for (int gq = 0; gq < 4; ++gq) {
            f32x2 g01 = gelu2((f32x2){ c[4*gq+0], c[4*gq+1] });
            f32x2 g23 = gelu2((f32x2){ c[4*gq+2], c[4*gq+3] });
            pw[2*gq+0] = pack2bf(g01.x, g01.y);
            pw[2*gq+1] = pack2bf(g23.x, g23.y);
        }
        B2[2*ut1+0] = frag_from_pk(pw[0], pw[1], pw[2], pw[3]);
        B2[2*ut1+1] = frag_from_pk(pw[4], pw[5], pw[6], pw[7]);
    }

    // ---- layers 2+3 fused per 32-u slice; A2 from swizzled LDS; b2 in C-init ----
    f32x16 acc3;
    #pragma unroll
    for (int q = 0; q < 16; ++q) acc3[q] = 0.0f;

    #pragma unroll
    for (int ut = 0; ut < 8; ++ut) {
        int u0 = ut * 32 + 4 * b;
        f32x16 c;
        #pragma unroll
        for (int gq = 0; gq < 4; ++gq) {
            f32x4 bq = *(const f32x4*)&b2s[u0 + 8 * gq];   // LDS broadcast
            c[4*gq+0] = bq[0]; c[4*gq+1] = bq[1]; c[4*gq+2] = bq[2]; c[4*gq+3] = bq[3];
        }
        {
            const int u = ut * 32 + l31;
            const char* rowbase = (const char*)w2l + u * 256;
            const int sw = (u & 15) << 4;
            #pragma unroll
            for (int kt = 0; kt < 8; ++kt) {
                bf16x8 a2 = *(const bf16x8*)(rowbase + ((kt * 32 + b * 16) ^ sw));
                c = __builtin_amdgcn_mfma_f32_32x32x16_bf16(a2, B2[kt], c, 0, 0, 0);
            }
        }

        unsigned int pw[8];
        #pragma unroll
        for (int gq = 0; gq < 4; ++gq) {
            f32x2 g01 = gelu2((f32x2){ c[4*gq+0], c[4*gq+1] });
            f32x2 g23 = gelu2((f32x2){ c[4*gq+2], c[4*gq+3] });
            pw[2*gq+0] = pack2bf(g01.x, g01.y);
            pw[2*gq+1] = pack2bf(g23.x, g23.y);
        }

        #pragma unroll
        for (int ki = 0; ki < 2; ++ki) {
            bf16x8 bfr = frag_from_pk(pw[4*ki+0], pw[4*ki+1], pw[4*ki+2], pw[4*ki+3]);
            bf16x8 a3  = *(const bf16x8*)&w3t[l31 * 256 + ut * 32 + ki * 16 + b * 8];
            acc3 = __builtin_amdgcn_mfma_f32_32x32x16_bf16(a3, bfr, acc3, 0, 0, 0);
        }
    }

    // ---- output: b==0 lane l31 owns edge g; shfl segmented scan, tail atomics ----
    if (b == 0) {
        float m0 = 0.0f, m1 = 0.0f, m2 = 0.0f;
        if (iidx >= 0) {
            m0 = (acc3[0] + b3[0]) * fy0;
            m1 = (acc3[1] + b3[1]) * fy1;
            m2 = (acc3[2] + b3[2]) * fy2;
        }
        // inclusive segmented scan over lanes 0..31 (x_index sorted -> segments contiguous)
        #pragma unroll
        for (int d = 1; d < 32; d <<= 1) {
            int   oi = __shfl(iidx, l31 - d, 64);
            float o0 = __shfl(m0,   l31 - d, 64);
            float o1 = __shfl(m1,   l31 - d, 64);
            float o2 = __shfl(m2,   l31 - d, 64);
            if (l31 >= d && oi == iidx) { m0 += o0; m1 += o1; m2 += o2; }
        }
        int ni = __shfl(iidx, l31 + 1, 64);   // lane 31 reads lane 32 (b=1, iidx=-1) -> tail
        bool tail = (iidx >= 0) && (l31 == 31 || ni != iidx);
        if (tail) {
            unsafeAtomicAdd(&out[iidx*3+0], m0);
            unsafeAtomicAdd(&out[iidx*3+1], m1);
            unsafeAtomicAdd(&out[iidx*3+2], m2);
        }
    }
}

// out[i] /= max(cnt_i, 1); cnt via binary search on sorted x_index
__global__ void finalize_div(float* __restrict__ out, const int* __restrict__ xidx,
                             int E, int nx) {
    int i = blockIdx.x * blockDim.x + threadIdx.x;
    if (i >= nx) return;
    int lo = 0, hi = E;
    while (lo < hi) { int mid = (lo + hi) >> 1; if (xidx[mid] < i) lo = mid + 1; else hi = mid; }
    int start = lo;
    hi = E;
    while (lo < hi) { int mid = (lo + hi) >> 1; if (xidx[mid] < i + 1) lo = mid + 1; else hi = mid; }
    int cnt = lo - start;
    float inv = 1.0f / (float)(cnt > 1 ? cnt : 1);
    out[i*3+0] *= inv;
    out[i*3+1] *= inv;
    out[i*3+2] *= inv;
}

extern "C" void kernel_launch(void* const* d_in, const int* in_sizes, int n_in,
                              void* d_out, int out_size, void* d_ws, size_t ws_size,
                              hipStream_t stream) {
    const float* y   = (const float*)d_in[0];
    const float* x   = (const float*)d_in[1];
    const float* fyp = (const float*)d_in[2];
    const int*   nbr = (const int*)d_in[3];
    const int*   xix = (const int*)d_in[4];
    const float* W1  = (const float*)d_in[5];
    const float* b1  = (const float*)d_in[6];
    const float* W2  = (const float*)d_in[7];
    const float* b2  = (const float*)d_in[8];
    const float* W3  = (const float*)d_in[9];
    const float* b3  = (const float*)d_in[10];
    float* out = (float*)d_out;

    int E  = in_sizes[3];
    int nx = in_sizes[1] / 3;
    __bf16* w2t  = (__bf16*)d_ws;                        // 32768 bf16 = 64 KB
    __bf16* w3t  = (__bf16*)((char*)d_ws + 65536);       // 8192 bf16 = 16 KB
    __bf16* w1tp = (__bf16*)((char*)d_ws + 81920);       // 2048 bf16 = 4 KB

    hipMemsetAsync(d_out, 0, (size_t)out_size * sizeof(float), stream);
    prep_weights<<<168, 256, 0, stream>>>(W2, W3, W1, b1, w2t, w3t, w1tp);

    int nblocks = (E + 255) / 256;
    edge_mlp<<<nblocks, 512, 0, stream>>>(y, x, fyp, nbr, xix, w1tp, w2t, b2, w3t, b3, out, E);

    finalize_div<<<(nx + 255) / 256, 256, 0, stream>>>(out, xix, E, nx);
}